// Round 2
// 14472.409 us; speedup vs baseline: 1.0715x; 1.0715x over previous
//
#include <hip/hip_runtime.h>
#include <cstdint>
#include <cstddef>
#include <math.h>

#define B_   32
#define S_   2048
#define IN_  128
#define H_   256
#define Q_   16
#define M_   64
#define D_   4      // layer-1 lag (LDS a-ring depth 8 > D+1)

__device__ __forceinline__ float4 ld4(const float* p) { return *(const float4*)p; }

#define AGLD(p)    __hip_atomic_load((p),  __ATOMIC_RELAXED, __HIP_MEMORY_SCOPE_AGENT)
#define AGST(p, v) __hip_atomic_store((p), (v), __ATOMIC_RELAXED, __HIP_MEMORY_SCOPE_AGENT)

// ---------------------------------------------------------------------------
// Fused 2-layer LSTM recurrence. 256 blocks = 32 rows x 8; 1 block/CU.
// Block owns 32 hidden cols of EACH layer (all 4 gates per col).
// Lane layout: (wave w, col-group rg = l>>3, k-chunk kc = l&7).
//   Each lane owns ONE column (col = n*32 + w*8 + rg) x 4 gates, and a
//   32-element k-chunk (k = 4*kc + 32*j + i). Dots are k-parallel:
//   ds_read_b128s hit 8 unique addresses/wave covering all 32 banks once
//   (same-address lanes broadcast -> conflict-free) + 3-step shfl_xor
//   butterfly over the 8 kc lanes. Gate combine, cell update, activation
//   and publish are fully IN-LANE -> no g_sh LDS round-trip, no mid-step
//   barrier, per-wave early publish.
// Whh0/Whh1/Wih0 chunks in VGPRs (320 f32/lane); Wih1 in LDS, padded
// row-major [128][257] so per-lane b128 reads start at bank (lr+4kc)%32 =
// uniform 2-way (free, m136). Read only off the critical path (xa1 for
// step u+1 computed during the exchange wait).
// Cross-block exchange: tagged dword pairs (tag<<16 | fp32-half) in a
// parity-2 ring, agent-scope relaxed atomics -> single-round-trip sync.
// All-fp32 arithmetic (bf16 anywhere shifts kNN top-3 picks -> 0.46 absmax).
// ---------------------------------------------------------------------------
__global__ __launch_bounds__(256, 1) void lstm2(
    const float* __restrict__ x,     // [B,S,128]
    const float* __restrict__ Wih0, const float* __restrict__ bih0,
    const float* __restrict__ bhh0, const float* __restrict__ Whh0,
    const float* __restrict__ Wih1, const float* __restrict__ bih1,
    const float* __restrict__ bhh1, const float* __restrict__ Whh1,
    float* __restrict__ out,         // [B,S,256]  (= d_out, layer-1 hidden)
    unsigned int* __restrict__ ex)   // [32][2q][2p][2plane][256] tagged dwords
{
  const int f = blockIdx.x;
  const int n = (f >> 3) & 7;              // block-in-row
  const int b = (f >> 6) * 8 + (f & 7);    // row (XCD-swizzled)

  const int tid = threadIdx.x;
  const int w   = tid >> 6;                // wave 0..3
  const int l   = tid & 63;
  const int kc  = l & 7;                   // k-chunk lane 0..7
  const int rg  = l >> 3;                  // col-in-wave 0..7
  const int wrg = w * 8 + rg;              // col-in-block 0..31
  const int col = n * 32 + wrg;            // global hidden col 0..255

  __shared__ float w1[128][257];           // Wih1 block slice, padded rows
  __shared__ float aring[8][256];          // last 8 layer-0 hidden vectors
  __shared__ float hring[2][256];          // layer-1 hidden, parity dbuf
  __shared__ float x_sh[2][IN_];

#pragma unroll
  for (int s2 = 0; s2 < 8; s2++) aring[s2][tid] = 0.0f;
  hring[0][tid] = 0.0f;
  hring[1][tid] = 0.0f;

  // --- register weights, chunk layout k = 4*kc + 32*j + i ---------------
  float4 wf0[4][8], wf1[4][8], wi0[4][4];
  float rb0[4], rb1[4];
#pragma unroll
  for (int g = 0; g < 4; g++) {
    const int row = g * 256 + col;
    const float* p0 = Whh0 + (size_t)row * 256 + 4 * kc;
    const float* p1 = Whh1 + (size_t)row * 256 + 4 * kc;
    const float* pi = Wih0 + (size_t)row * 128 + 4 * kc;
#pragma unroll
    for (int j = 0; j < 8; j++) {
      wf0[g][j] = ld4(p0 + 32 * j);
      wf1[g][j] = ld4(p1 + 32 * j);
    }
#pragma unroll
    for (int j = 0; j < 4; j++) wi0[g][j] = ld4(pi + 32 * j);
    rb0[g] = bih0[row] + bhh0[row];
    rb1[g] = bih1[row] + bhh1[row];
    // stage this lane's Wih1 chunk into w1[g*32+wrg][4*kc + 32*j .. +3]
    const float* pw = Wih1 + (size_t)row * 256 + 4 * kc;
    float* dst = &w1[g * 32 + wrg][4 * kc];
#pragma unroll
    for (int j = 0; j < 8; j++) *(float4*)(dst + 32 * j) = ld4(pw + 32 * j);
  }

  const float* xrow = x + (size_t)b * S_ * IN_;
  float* outp = out + (size_t)b * S_ * H_;
  unsigned int* exb = ex + (size_t)b * 2048;
  // addr(q,p,plane,e) = exb + (((q*2+p)*2+plane)<<8) + e

  if (tid < IN_) {
    x_sh[0][tid] = xrow[tid];
    x_sh[1][tid] = xrow[IN_ + tid];
  }
  float xreg = (tid < IN_) ? xrow[(size_t)2 * IN_ + tid] : 0.0f;
  float cst0 = 0.0f, cst1 = 0.0f;          // cell states (replicated / kc)
  float xa0s[4], xa1s[4] = {0, 0, 0, 0};
  __syncthreads();

  // xa0 for t=0
  {
    const float* xb = x_sh[0];
    float4 xv[4];
#pragma unroll
    for (int j = 0; j < 4; j++) xv[j] = ld4(xb + 4 * kc + 32 * j);
#pragma unroll
    for (int g = 0; g < 4; g++) {
      float4 s4 = {0, 0, 0, 0};
#pragma unroll
      for (int j = 0; j < 4; j++) {
        s4.x += wi0[g][j].x * xv[j].x; s4.y += wi0[g][j].y * xv[j].y;
        s4.z += wi0[g][j].z * xv[j].z; s4.w += wi0[g][j].w * xv[j].w;
      }
      float s = (s4.x + s4.y) + (s4.z + s4.w);
      s += __shfl_xor(s, 1); s += __shfl_xor(s, 2); s += __shfl_xor(s, 4);
      xa0s[g] = s + rb0[g];
    }
  }

  bool dead = false;
  for (int t = 0; t < S_ + D_; ++t) {
    const bool doA = (t < S_);
    const int  u   = t - D_;
    const bool doH = (u >= 0);

    // ---- 1. k-parallel gate dots + in-lane cells + early publish -------
    if (doA) {
      const float* ap = aring[(t - 1) & 7];
      float4 av[8];
#pragma unroll
      for (int j = 0; j < 8; j++) av[j] = ld4(ap + 4 * kc + 32 * j);
      float gv[4];
#pragma unroll
      for (int g = 0; g < 4; g++) {
        float4 s4 = {0, 0, 0, 0};
#pragma unroll
        for (int j = 0; j < 8; j++) {
          s4.x += wf0[g][j].x * av[j].x; s4.y += wf0[g][j].y * av[j].y;
          s4.z += wf0[g][j].z * av[j].z; s4.w += wf0[g][j].w * av[j].w;
        }
        float s = (s4.x + s4.y) + (s4.z + s4.w);
        s += __shfl_xor(s, 1); s += __shfl_xor(s, 2); s += __shfl_xor(s, 4);
        gv[g] = s + xa0s[g];
      }
      float ig = 1.0f / (1.0f + expf(-gv[0]));
      float fg = 1.0f / (1.0f + expf(-gv[1]));
      float cg = tanhf(gv[2]);
      float og = 1.0f / (1.0f + expf(-gv[3]));
      cst0 = fg * cst0 + ig * cg;
      float a = og * tanhf(cst0);
      if (kc == 0) {                       // 8 lanes/wave publish own cols
        unsigned bits = __float_as_uint(a);
        unsigned tag  = (unsigned)(t + 1) << 16;
        const int p = t & 1;
        AGST(exb + (((0 * 2 + p) * 2 + 0) << 8) + col, tag | (bits >> 16));
        AGST(exb + (((0 * 2 + p) * 2 + 1) << 8) + col, tag | (bits & 0xffffu));
      }
    }
    if (doH) {
      const float* hp = hring[(t - 1) & 1];
      float4 hv[8];
#pragma unroll
      for (int j = 0; j < 8; j++) hv[j] = ld4(hp + 4 * kc + 32 * j);
      float gv[4];
#pragma unroll
      for (int g = 0; g < 4; g++) {
        float4 s4 = {0, 0, 0, 0};
#pragma unroll
        for (int j = 0; j < 8; j++) {
          s4.x += wf1[g][j].x * hv[j].x; s4.y += wf1[g][j].y * hv[j].y;
          s4.z += wf1[g][j].z * hv[j].z; s4.w += wf1[g][j].w * hv[j].w;
        }
        float s = (s4.x + s4.y) + (s4.z + s4.w);
        s += __shfl_xor(s, 1); s += __shfl_xor(s, 2); s += __shfl_xor(s, 4);
        gv[g] = s + xa1s[g];
      }
      float ig = 1.0f / (1.0f + expf(-gv[0]));
      float fg = 1.0f / (1.0f + expf(-gv[1]));
      float cg = tanhf(gv[2]);
      float og = 1.0f / (1.0f + expf(-gv[3]));
      cst1 = fg * cst1 + ig * cg;
      float h = og * tanhf(cst1);
      if (kc == 0) {
        outp[(size_t)u * H_ + col] = h;    // plain store for epilogue
        unsigned bits = __float_as_uint(h);
        unsigned tag  = (unsigned)(u + 1) << 16;
        const int p = u & 1;
        AGST(exb + (((1 * 2 + p) * 2 + 0) << 8) + col, tag | (bits >> 16));
        AGST(exb + (((1 * 2 + p) * 2 + 1) << 8) + col, tag | (bits & 0xffffu));
      }
    }

    // ---- 3. off-critical-path work (overlaps exchange latency) ---------
    // 3a. next xa0 from x_sh
    if (t + 1 < S_) {
      const float* xb = x_sh[(t + 1) & 1];
      float4 xv[4];
#pragma unroll
      for (int j = 0; j < 4; j++) xv[j] = ld4(xb + 4 * kc + 32 * j);
#pragma unroll
      for (int g = 0; g < 4; g++) {
        float4 s4 = {0, 0, 0, 0};
#pragma unroll
        for (int j = 0; j < 4; j++) {
          s4.x += wi0[g][j].x * xv[j].x; s4.y += wi0[g][j].y * xv[j].y;
          s4.z += wi0[g][j].z * xv[j].z; s4.w += wi0[g][j].w * xv[j].w;
        }
        float s = (s4.x + s4.y) + (s4.z + s4.w);
        s += __shfl_xor(s, 1); s += __shfl_xor(s, 2); s += __shfl_xor(s, 4);
        xa0s[g] = s + rb0[g];
      }
    }
    // 3b. xa1 for layer-1 step v = u+1: w1 (padded b128 stream) x aring[v]
    {
      const int v = t - D_ + 1;
      if (v >= 0 && v < S_) {
        const float* avp = aring[v & 7];
        float4 av[8];
#pragma unroll
        for (int j = 0; j < 8; j++) av[j] = ld4(avp + 4 * kc + 32 * j);
#pragma unroll
        for (int g = 0; g < 4; g++) {
          const float* wr = &w1[g * 32 + wrg][4 * kc];
          float4 s4 = {0, 0, 0, 0};
#pragma unroll
          for (int j = 0; j < 8; j++) {
            float4 wv = ld4(wr + 32 * j);
            s4.x += wv.x * av[j].x; s4.y += wv.y * av[j].y;
            s4.z += wv.z * av[j].z; s4.w += wv.w * av[j].w;
          }
          float s = (s4.x + s4.y) + (s4.z + s4.w);
          s += __shfl_xor(s, 1); s += __shfl_xor(s, 2); s += __shfl_xor(s, 4);
          xa1s[g] = s + rb1[g];
        }
      }
    }
    // 3c. x prefetch
    float xreg_n = 0.0f;
    if (tid < IN_ && t + 2 < S_) {
      int tn = (t + 3 < S_) ? t + 3 : S_ - 1;
      xreg_n = xrow[(size_t)tn * IN_ + tid];
    }

    // ---- 4. tagged gathers (single round trip) -------------------------
    if (!dead && (doA || doH)) {
      const unsigned eA = (unsigned)(t + 1) & 0xffffu;
      const unsigned eH = (unsigned)(u + 1) & 0xffffu;
      const int pa = t & 1, ph = u & 1;
      unsigned int* aHi = exb + (((0 * 2 + pa) * 2 + 0) << 8) + tid;
      unsigned int* aLo = exb + (((0 * 2 + pa) * 2 + 1) << 8) + tid;
      unsigned int* hHi = exb + (((1 * 2 + ph) * 2 + 0) << 8) + tid;
      unsigned int* hLo = exb + (((1 * 2 + ph) * 2 + 1) << 8) + tid;
      unsigned a0v = 0, a1v = 0, h0v = 0, h1v = 0;
      bool needA = doA, needH = doH;
      unsigned guard = 0;
      while (true) {
        if (needA) {
          a0v = AGLD(aHi); a1v = AGLD(aLo);
          if ((a0v >> 16) == eA && (a1v >> 16) == eA) needA = false;
        }
        if (needH) {
          h0v = AGLD(hHi); h1v = AGLD(hLo);
          if ((h0v >> 16) == eH && (h1v >> 16) == eH) needH = false;
        }
        if (!needA && !needH) break;
        if (++guard >= (1u << 20)) { dead = true; break; }
      }
      if (doA) aring[t & 7][tid] = __uint_as_float((a0v << 16) | (a1v & 0xffffu));
      if (doH) hring[t & 1][tid] = __uint_as_float((h0v << 16) | (h1v & 0xffffu));
    }
    if (tid < IN_ && t < S_) x_sh[t & 1][tid] = xreg;
    xreg = xreg_n;
    __syncthreads();
  }
}

// ---------------------------------------------------------------------------
// kNN memory read. One wave per token. enh = qw * enhanced  [MT,256] fp32.
// ---------------------------------------------------------------------------
__global__ __launch_bounds__(256) void knn_enh(
    const float* __restrict__ lstm, const float* __restrict__ Wcq,
    const float* __restrict__ bcq, const float* __restrict__ keys,
    const float* __restrict__ vals, const float* __restrict__ qwp,
    float* __restrict__ enh)
{
  const int tid  = threadIdx.x;
  const int wave = tid >> 6, lane = tid & 63;
  const int t = blockIdx.x * 4 + wave;

  __shared__ float xsh[4][256];
  __shared__ float qsh[4][16];

  const float* xrow = lstm + (size_t)t * H_;
  float4 x4 = ld4(xrow + lane * 4);
  *(float4*)&xsh[wave][lane * 4] = x4;
  __syncthreads();

  const int j = lane & 15, seg = lane >> 4;
  const float* wrow = Wcq + j * H_ + seg * 64;
  const float* xseg = &xsh[wave][seg * 64];
  float p = 0.0f;
#pragma unroll
  for (int c = 0; c < 64; c += 4) {
    float4 w4 = ld4(wrow + c);
    p += w4.x * xseg[c] + w4.y * xseg[c + 1] + w4.z * xseg[c + 2] + w4.w * xseg[c + 3];
  }
  p += __shfl_xor(p, 16);
  p += __shfl_xor(p, 32);
  float q = tanhf(p + bcq[j]);

  float sq = q * q;
  sq += __shfl_xor(sq, 1); sq += __shfl_xor(sq, 2);
  sq += __shfl_xor(sq, 4); sq += __shfl_xor(sq, 8);
  float qn = q / (sqrtf(sq) + 1e-8f);
  if (lane < 16) qsh[wave][lane] = qn;
  __syncthreads();

  const int m = lane;
  const float* krow = keys + m * Q_;
  float kv[16]; float kn2 = 0.0f;
#pragma unroll
  for (int jj = 0; jj < 16; jj++) { kv[jj] = krow[jj]; kn2 += kv[jj] * kv[jj]; }
  float rn = 1.0f / (sqrtf(kn2) + 1e-8f);
  float sim = 0.0f;
#pragma unroll
  for (int jj = 0; jj < 16; jj++) sim += qsh[wave][jj] * kv[jj];
  sim *= rn;

  float rem = sim;
  float tv[3]; int ti[3];
#pragma unroll
  for (int k = 0; k < 3; k++) {
    float v = rem; int idx = m;
#pragma unroll
    for (int d = 1; d < 64; d <<= 1) {
      float ov = __shfl_xor(v, d);
      int   oi = __shfl_xor(idx, d);
      if (ov > v || (ov == v && oi < idx)) { v = ov; idx = oi; }
    }
    tv[k] = v; ti[k] = idx;
    if (m == idx) rem = -INFINITY;
  }
  float tot = tv[0] + tv[1] + tv[2];

  float ex = 0, ey = 0, ez = 0, ew = 0;
#pragma unroll
  for (int k = 0; k < 3; k++) {
    float4 vv = ld4(vals + (size_t)ti[k] * H_ + lane * 4);
    ex += tv[k] * vv.x; ey += tv[k] * vv.y;
    ez += tv[k] * vv.z; ew += tv[k] * vv.w;
  }
  float inv = (tot > 0.0f) ? 1.0f / tot : 0.0f;
  const float qw = qwp[0];

  float4 o;
  o.x = qw * ex * inv; o.y = qw * ey * inv;
  o.z = qw * ez * inv; o.w = qw * ew * inv;
  *(float4*)&enh[(size_t)t * H_ + lane * 4] = o;
}

// ---------------------------------------------------------------------------
// Final projection, IN-PLACE on io (= d_out). Block owns 64 rows x all 256
// cols; reads its own rows, writes after the K-loop -> race-free in-place.
// ---------------------------------------------------------------------------
__global__ __launch_bounds__(256) void gemm_cat(
    float* __restrict__ io, const float* __restrict__ A2,
    const float* __restrict__ Bw, const float* __restrict__ bias,
    const float* __restrict__ cwp)
{
  __shared__ float As[16][68];
  __shared__ float Bs[16][260];
  const int tid  = threadIdx.x;
  const int row0 = blockIdx.x * 64;
  const int tx = tid & 15, ty = tid >> 4;
  const int lr = tid >> 2;
  const int lk = (tid & 3) << 2;
  const float cw = cwp[0];

  float acc[4][16];
#pragma unroll
  for (int i = 0; i < 4; i++)
#pragma unroll
    for (int j = 0; j < 16; j++) acc[i][j] = 0.0f;

  for (int k0 = 0; k0 < 512; k0 += 16) {
    float4 av;
    if (k0 < 256) {
      av = ld4(io + (size_t)(row0 + lr) * 256 + k0 + lk);
      av.x *= cw; av.y *= cw; av.z *= cw; av.w *= cw;
    } else {
      av = ld4(A2 + (size_t)(row0 + lr) * 256 + (k0 - 256) + lk);
    }
    As[lk + 0][lr] = av.x; As[lk + 1][lr] = av.y;
    As[lk + 2][lr] = av.z; As[lk + 3][lr] = av.w;
    const float* bp = Bw + (size_t)tid * 512 + k0;
#pragma unroll
    for (int q = 0; q < 4; q++) {
      float4 b4 = ld4(bp + 4 * q);
      Bs[4 * q + 0][tid] = b4.x; Bs[4 * q + 1][tid] = b4.y;
      Bs[4 * q + 2][tid] = b4.z; Bs[4 * q + 3][tid] = b4.w;
    }
    __syncthreads();
#pragma unroll
    for (int k = 0; k < 16; k++) {
      float4 a4 = *(const float4*)&As[k][ty << 2];
      float aa[4] = {a4.x, a4.y, a4.z, a4.w};
#pragma unroll
      for (int cc = 0; cc < 4; cc++) {
        float4 b4 = *(const float4*)&Bs[k][cc * 64 + (tx << 2)];
        float bb[4] = {b4.x, b4.y, b4.z, b4.w};
#pragma unroll
        for (int i = 0; i < 4; i++)
#pragma unroll
          for (int jj = 0; jj < 4; jj++) acc[i][cc * 4 + jj] += aa[i] * bb[jj];
      }
    }
    __syncthreads();
  }

#pragma unroll
  for (int i = 0; i < 4; i++) {
#pragma unroll
    for (int cc = 0; cc < 4; cc++) {
      int c0 = cc * 64 + (tx << 2);
      float4 o;
      o.x = acc[i][cc * 4 + 0] + bias[c0 + 0];
      o.y = acc[i][cc * 4 + 1] + bias[c0 + 1];
      o.z = acc[i][cc * 4 + 2] + bias[c0 + 2];
      o.w = acc[i][cc * 4 + 3] + bias[c0 + 3];
      *(float4*)&io[(size_t)(row0 + (ty << 2) + i) * 256 + c0] = o;
    }
  }
}

// ---------------------------------------------------------------------------
extern "C" void kernel_launch(void* const* d_in, const int* in_sizes, int n_in,
                              void* d_out, int out_size, void* d_ws, size_t ws_size,
                              hipStream_t stream)
{
  const float* x    = (const float*)d_in[0];
  const float* Wih0 = (const float*)d_in[1];
  const float* Whh0 = (const float*)d_in[2];
  const float* bih0 = (const float*)d_in[3];
  const float* bhh0 = (const float*)d_in[4];
  const float* Wih1 = (const float*)d_in[5];
  const float* Whh1 = (const float*)d_in[6];
  const float* bih1 = (const float*)d_in[7];
  const float* bhh1 = (const float*)d_in[8];
  const float* Wcq  = (const float*)d_in[9];
  const float* bcq  = (const float*)d_in[10];
  const float* keys = (const float*)d_in[11];
  const float* vals = (const float*)d_in[12];
  const float* Wout = (const float*)d_in[13];
  const float* bout = (const float*)d_in[14];
  const float* cw   = (const float*)d_in[15];
  const float* qw   = (const float*)d_in[16];
  float* out = (float*)d_out;

  // ws: [exchange 256 KB (dead after lstm2)] overlapped with enh [MT,256] f32.
  const size_t HE = (size_t)B_ * S_ * H_;
  if (ws_size < HE * sizeof(float)) return;   // 67.1 MB (round-4 proven OK)
  unsigned int* ex = (unsigned int*)d_ws;
  float* enh = (float*)d_ws;

  const int MT = B_ * S_;
  dim3 blk(256);

  hipMemsetAsync(ex, 0, (size_t)32 * 2048 * sizeof(unsigned int), stream);
  lstm2<<<dim3(256), blk, 0, stream>>>(x, Wih0, bih0, bhh0, Whh0,
                                       Wih1, bih1, bhh1, Whh1, out, ex);

  knn_enh<<<dim3(MT / 4), blk, 0, stream>>>(out, Wcq, bcq, keys, vals, qw, enh);

  gemm_cat<<<dim3(MT / 64), blk, 0, stream>>>(out, enh, Wout, bout, cw);
}